// Round 7
// baseline (253.861 us; speedup 1.0000x reference)
//
#include <hip/hip_runtime.h>
#include <hip/hip_bf16.h>

// Problem constants
#define BATCH   4096
#define HIDDEN  128
#define SESS    50
#define KTOT    4096
#define NSPL    16                          // split-K for MFMA path
#define NB      ((size_t)BATCH * HIDDEN)    // 524288 elems per (B,H) buffer

typedef __bf16 bf16x8 __attribute__((ext_vector_type(8)));
typedef float  f32x4  __attribute__((ext_vector_type(4)));
typedef unsigned char uchar;

__device__ __forceinline__ f32x4 mfma_bf16(bf16x8 a, bf16x8 b, f32x4 c) {
    return __builtin_amdgcn_mfma_f32_16x16x32_bf16(a, b, c, 0, 0, 0);
}

// Packed B layout: elem(k,h) -> (k>>3)*1024 + (h>>4)*128 + (h&15)*8 + (k&7)
// Reader (lane lo=h-within-tile, quad=k-group): contiguous 16B per frag;
// each wave streams contiguous 8KB per 32-k step.

// ---------------------------------------------------------------------------
// PROBE (R5/R6-validated): decode 16x16x32 bf16 MFMA C/D layout + exact check.
// ---------------------------------------------------------------------------
__global__ __launch_bounds__(64)
void probe_kernel(int* __restrict__ flag, uchar* __restrict__ rtab,
                  uchar* __restrict__ ctab) {
    __shared__ float As[16][32];
    __shared__ float Bs[32][16];
    __shared__ int cnt[256];
    const int lane = threadIdx.x;
    for (int idx = lane; idx < 512; idx += 64) {
        const int m = idx >> 5, k = idx & 31;
        As[m][k] = (float)(((m * 5 + k * 3) % 17) - 8);
        const int kb = idx >> 4, n = idx & 15;
        Bs[kb][n] = (float)(((kb * 7 + n * 11) % 17) - 8);
    }
    for (int i = lane; i < 256; i += 64) cnt[i] = 0;
    __syncthreads();

    const int lo = lane & 15, quad = lane >> 4;
    bf16x8 a, b, a1, b1, a2, b2;
#pragma unroll
    for (int j = 0; j < 8; ++j) {
        a[j]  = (__bf16)As[lo][quad * 8 + j];
        b[j]  = (__bf16)Bs[quad * 8 + j][lo];
        a1[j] = (__bf16)0.f; b1[j] = (__bf16)0.f;
        a2[j] = (__bf16)0.f; b2[j] = (__bf16)0.f;
    }
    if (quad == 0) {
        a1[0] = (__bf16)(float)lo;  b1[0] = (__bf16)1.f;       // D1[m][n] = m
        a2[0] = (__bf16)1.f;        b2[0] = (__bf16)(float)lo; // D2[m][n] = n
    }
    const f32x4 z = {0.f, 0.f, 0.f, 0.f};
    f32x4 d  = mfma_bf16(a,  b,  z);
    f32x4 d1 = mfma_bf16(a1, b1, z);
    f32x4 d2 = mfma_bf16(a2, b2, z);

    bool ok = true;
    int ms[4], ns[4];
#pragma unroll
    for (int r = 0; r < 4; ++r) {
        const int m = (int)d1[r], n = (int)d2[r];
        ok = ok && ((float)m == d1[r]) && ((float)n == d2[r]) &&
             (m >= 0) && (m < 16) && (n >= 0) && (n < 16);
        ms[r] = m & 15; ns[r] = n & 15;
        float ref = 0.f;
        for (int k = 0; k < 32; ++k) ref += As[ms[r]][k] * Bs[k][ns[r]];
        ok = ok && (d[r] == ref);   // exact: integer values < 2^24
        atomicAdd(&cnt[ms[r] * 16 + ns[r]], 1);
    }
    __syncthreads();
    bool comp = true;
    for (int i = lane; i < 256; i += 64) comp = comp && (cnt[i] == 1);

    const unsigned long long b_ok   = __ballot(ok);
    const unsigned long long b_comp = __ballot(comp);
#pragma unroll
    for (int r = 0; r < 4; ++r) {
        rtab[lane * 4 + r] = (uchar)ms[r];
        ctab[lane * 4 + r] = (uchar)ns[r];
    }
    if (lane == 0)
        *flag = (b_ok == ~0ULL && b_comp == ~0ULL) ? 1 : 0;
}

// ---------------------------------------------------------------------------
// Gather (R6-validated): E[b][h] = sum_s emb[items[b][s]][h]
//   -> Ef (fp32 row-major, fallback) and ETp (bf16, packed MFMA-B layout)
// ---------------------------------------------------------------------------
__global__ __launch_bounds__(256)
void gather_sum_kernel(const float* __restrict__ emb,
                       const int* __restrict__ items32,
                       float* __restrict__ Ef,
                       __bf16* __restrict__ ETp) {
    __shared__ int sidx[2][SESS];
    __shared__ f32x4 red[2][4][32];
    const int t  = threadIdx.x;
    const int b0 = blockIdx.x * 2;
    const bool is64 = (items32[1] | items32[3] | items32[5] | items32[7] |
                       items32[9] | items32[11] | items32[13] | items32[15]) == 0;
    if (t < 2 * SESS) {
        sidx[t / SESS][t % SESS] =
            is64 ? (int)((const long long*)items32)[(long)b0 * SESS + t]
                 : items32[b0 * SESS + t];
    }
    __syncthreads();
    const int r  = t >> 7;
    const int g  = (t >> 5) & 3;
    const int c4 = (t & 31) * 4;
    f32x4 acc = {0.f, 0.f, 0.f, 0.f};
#pragma unroll
    for (int s = g; s < SESS; s += 4) {
        acc += *(const f32x4*)(emb + (long)sidx[r][s] * HIDDEN + c4);
    }
    red[r][g][t & 31] = acc;
    __syncthreads();
    if (g == 0) {
        const int b = b0 + r;
        const f32x4 v = red[r][0][t & 31] + red[r][1][t & 31] +
                        red[r][2][t & 31] + red[r][3][t & 31];
        *(f32x4*)(Ef + (long)b * HIDDEN + c4) = v;
        const long pb = ((long)(b >> 3) << 10) + (b & 7) + ((c4 >> 4) << 7);
#pragma unroll
        for (int j = 0; j < 4; ++j)
            ETp[pb + ((c4 & 15) + j) * 8] = (__bf16)v[j];
    }
}

// ---------------------------------------------------------------------------
// MFMA GEMM v3 (flag==1): 1-wave blocks, M-tile 32 rows/wave, split-K 16.
// grid (BATCH/32=128, NSPL=16). Wave owns rows r0..r0+31, k-slice 256
// (8 iters of 32-k). Per iter: 4 X f32x4 loads (HBM stream) + 8 packed-B
// bf16x8 loads (L2-resident, traffic 8x lower than R6) + 16 MFMAs.
// No LDS, no barriers; full unroll + VGPR cap 256 lets the compiler
// software-pipeline several iterations of loads.
// Partial out: Pp[sy] (fp32, row-major 4096x128), epilogue via probed tables.
// ---------------------------------------------------------------------------
__global__ __launch_bounds__(64, 2)
void gemm_mfma_kernel(const float* __restrict__ X,
                      const __bf16* __restrict__ BTp,
                      const int* __restrict__ flag,
                      const uchar* __restrict__ rtab,
                      const uchar* __restrict__ ctab,
                      float* __restrict__ Pp) {
    if (*flag != 1) return;
    const int lane = threadIdx.x;
    const int lo   = lane & 15;
    const int quad = lane >> 4;
    const int r0   = blockIdx.x * 32;
    const int sy   = blockIdx.y;
    const int kb   = sy * 256;

    const unsigned rt4 = ((const unsigned*)rtab)[lane];
    const unsigned ct4 = ((const unsigned*)ctab)[lane];

    f32x4 acc0[8], acc1[8];
#pragma unroll
    for (int i = 0; i < 8; ++i) {
        acc0[i] = (f32x4){0.f, 0.f, 0.f, 0.f};
        acc1[i] = (f32x4){0.f, 0.f, 0.f, 0.f};
    }

    const float*  ap0 = X + (long)(r0 + lo) * KTOT + kb + quad * 8;
    const float*  ap1 = ap0 + 16 * KTOT;
    const __bf16* bp  = BTp + (((long)(kb >> 3) + quad) << 10) + lo * 8;

#pragma unroll
    for (int it = 0; it < 8; ++it) {
        const f32x4 x00 = *(const f32x4*)(ap0 + it * 32);
        const f32x4 x01 = *(const f32x4*)(ap0 + it * 32 + 4);
        const f32x4 x10 = *(const f32x4*)(ap1 + it * 32);
        const f32x4 x11 = *(const f32x4*)(ap1 + it * 32 + 4);
        bf16x8 b[8];
#pragma unroll
        for (int nt = 0; nt < 8; ++nt)
            b[nt] = *(const bf16x8*)(bp + (long)it * 4096 + nt * 128);
        bf16x8 a0, a1;
        a0[0] = (__bf16)x00[0]; a0[1] = (__bf16)x00[1];
        a0[2] = (__bf16)x00[2]; a0[3] = (__bf16)x00[3];
        a0[4] = (__bf16)x01[0]; a0[5] = (__bf16)x01[1];
        a0[6] = (__bf16)x01[2]; a0[7] = (__bf16)x01[3];
        a1[0] = (__bf16)x10[0]; a1[1] = (__bf16)x10[1];
        a1[2] = (__bf16)x10[2]; a1[3] = (__bf16)x10[3];
        a1[4] = (__bf16)x11[0]; a1[5] = (__bf16)x11[1];
        a1[6] = (__bf16)x11[2]; a1[7] = (__bf16)x11[3];
#pragma unroll
        for (int nt = 0; nt < 8; ++nt) {
            acc0[nt] = mfma_bf16(a0, b[nt], acc0[nt]);
            acc1[nt] = mfma_bf16(a1, b[nt], acc1[nt]);
        }
    }

    float* outp = Pp + (size_t)sy * NB;
#pragma unroll
    for (int r = 0; r < 4; ++r) {
        const int dr = (rt4 >> (8 * r)) & 255;
        const int dc = (ct4 >> (8 * r)) & 255;
#pragma unroll
        for (int nt = 0; nt < 8; ++nt) {
            outp[(long)(r0 + dr) * HIDDEN + nt * 16 + dc]      = acc0[nt][r];
            outp[(long)(r0 + 16 + dr) * HIDDEN + nt * 16 + dc] = acc1[nt][r];
        }
    }
}

// ---------------------------------------------------------------------------
// reduce16 (flag==1): T = sum of 16 partials -> TTp (packed bf16 B-operand).
// grid 512 x 256.
// ---------------------------------------------------------------------------
__global__ __launch_bounds__(256)
void reduce16_kernel(const float* __restrict__ Pp, const int* __restrict__ flag,
                     __bf16* __restrict__ TTp) {
    if (*flag != 1) return;
    const size_t i = ((size_t)blockIdx.x * 256 + threadIdx.x) * 4;
    f32x4 a = {0.f, 0.f, 0.f, 0.f};
#pragma unroll
    for (int s = 0; s < NSPL; ++s)
        a += *(const f32x4*)(Pp + (size_t)s * NB + i);
    const int b  = (int)(i >> 7);
    const int h0 = (int)(i & 127);
    const long pb = ((long)(b >> 3) << 10) + (b & 7) + ((h0 >> 4) << 7);
#pragma unroll
    for (int j = 0; j < 4; ++j)
        TTp[pb + ((h0 & 15) + j) * 8] = (__bf16)a[j];
}

// ---------------------------------------------------------------------------
// reduce_norm16 (flag==1): out[row] = normalize( sum of 16 partials ).
// ---------------------------------------------------------------------------
__global__ __launch_bounds__(128)
void reduce_norm16_kernel(const float* __restrict__ Rp,
                          const int* __restrict__ flag,
                          float* __restrict__ out) {
    if (*flag != 1) return;
    __shared__ float s[128];
    const int row = blockIdx.x;
    const int h   = threadIdx.x;
    const size_t i = (size_t)row * HIDDEN + h;
    float v = 0.f;
#pragma unroll
    for (int k = 0; k < NSPL; ++k) v += Rp[(size_t)k * NB + i];
    s[h] = v * v;
    __syncthreads();
#pragma unroll
    for (int o = 64; o > 0; o >>= 1) {
        if (h < o) s[h] += s[h + o];
        __syncthreads();
    }
    out[i] = v * rsqrtf(s[0]);
}

// ---------------------------------------------------------------------------
// fp32 VALU fallback path (flag != 1) — R4-proven structure, 4-way split-K.
// ---------------------------------------------------------------------------
__global__ __launch_bounds__(256)
void gemm_fp32_kernel(const float* __restrict__ X,
                      const float* __restrict__ B,
                      const int* __restrict__ flag,
                      float* __restrict__ Q) {
    if (*flag == 1) return;
    const int tid = threadIdx.x;
    const int cg4 = (tid & 31) * 4;
    const int rg  = tid >> 5;
    const int r0  = blockIdx.x * 32 + rg * 4;
    const int sy  = blockIdx.y;
    const int ks  = sy * 1024;
    float* outp = Q + (size_t)sy * NB;

    f32x4 acc[4];
#pragma unroll
    for (int j = 0; j < 4; ++j) acc[j] = (f32x4){0.f, 0.f, 0.f, 0.f};

    const float* Bp = B + (long)ks * HIDDEN + cg4;
    const float* Xp = X + (long)r0 * KTOT + ks;

    for (int k = 0; k < 1024; k += 4) {
        const f32x4 b0 = *(const f32x4*)(Bp + (long)(k + 0) * HIDDEN);
        const f32x4 b1 = *(const f32x4*)(Bp + (long)(k + 1) * HIDDEN);
        const f32x4 b2 = *(const f32x4*)(Bp + (long)(k + 2) * HIDDEN);
        const f32x4 b3 = *(const f32x4*)(Bp + (long)(k + 3) * HIDDEN);
#pragma unroll
        for (int j = 0; j < 4; ++j) {
            const f32x4 x = *(const f32x4*)(Xp + (long)j * KTOT + k);
            acc[j] += x[0] * b0;
            acc[j] += x[1] * b1;
            acc[j] += x[2] * b2;
            acc[j] += x[3] * b3;
        }
    }
#pragma unroll
    for (int j = 0; j < 4; ++j)
        *(f32x4*)(outp + (long)(r0 + j) * HIDDEN + cg4) = acc[j];
}

__global__ __launch_bounds__(256)
void reduce4f_kernel(const float* __restrict__ Q, const int* __restrict__ flag,
                     float* __restrict__ Tf) {
    if (*flag == 1) return;
    const size_t i = ((size_t)blockIdx.x * 256 + threadIdx.x) * 4;
    f32x4 a = *(const f32x4*)(Q + i);
    a += *(const f32x4*)(Q + NB + i);
    a += *(const f32x4*)(Q + 2 * NB + i);
    a += *(const f32x4*)(Q + 3 * NB + i);
    *(f32x4*)(Tf + i) = a;
}

__global__ __launch_bounds__(128)
void reduce_norm4f_kernel(const float* __restrict__ Q,
                          const int* __restrict__ flag,
                          float* __restrict__ out) {
    if (*flag == 1) return;
    __shared__ float s[128];
    const int row = blockIdx.x;
    const int h   = threadIdx.x;
    const size_t i = (size_t)row * HIDDEN + h;
    const float v = Q[i] + Q[NB + i] + Q[2 * NB + i] + Q[3 * NB + i];
    s[h] = v * v;
    __syncthreads();
#pragma unroll
    for (int o = 64; o > 0; o >>= 1) {
        if (h < o) s[h] += s[h + o];
        __syncthreads();
    }
    out[i] = v * rsqrtf(s[0]);
}

// ---------------------------------------------------------------------------
// out = normalize_rows( D @ (A @ E) )   [associativity: 137 GF -> 8.6 GF]
// ws: 1KB hdr | Ef 2MB | ETp 1MB | TTp 1MB | Tp16 32MB | Rp16 32MB
//     | Tf 2MB | Tq4 8MB | Rq4 8MB   (~86 MB)
// ---------------------------------------------------------------------------
extern "C" void kernel_launch(void* const* d_in, const int* in_sizes, int n_in,
                              void* d_out, int out_size, void* d_ws, size_t ws_size,
                              hipStream_t stream) {
    const float* emb   = (const float*)d_in[0];
    const int*   items = (const int*)d_in[1];
    const float* A     = (const float*)d_in[2];
    const float* D     = (const float*)d_in[3];
    float* out = (float*)d_out;

    uchar* base = (uchar*)d_ws;
    int*   flag = (int*)base;
    uchar* rtab = base + 64;
    uchar* ctab = base + 320;
    float*  Ef   = (float*)(base + 1024);
    __bf16* ETp  = (__bf16*)(Ef + NB);
    __bf16* TTp  = ETp + NB;
    float*  Tp16 = (float*)(TTp + NB);
    float*  Rp16 = Tp16 + NSPL * NB;
    float*  Tf   = Rp16 + NSPL * NB;
    float*  Tq   = Tf + NB;
    float*  Rq   = Tq + 4 * NB;

    probe_kernel<<<1, 64, 0, stream>>>(flag, rtab, ctab);
    gather_sum_kernel<<<BATCH / 2, 256, 0, stream>>>(emb, items, Ef, ETp);

    // Phase 1: T = A @ E
    gemm_mfma_kernel<<<dim3(BATCH / 32, NSPL), 64, 0, stream>>>(A, ETp, flag, rtab, ctab, Tp16);
    gemm_fp32_kernel<<<dim3(BATCH / 32, 4), 256, 0, stream>>>(A, Ef, flag, Tq);
    reduce16_kernel<<<512, 256, 0, stream>>>(Tp16, flag, TTp);
    reduce4f_kernel<<<512, 256, 0, stream>>>(Tq, flag, Tf);

    // Phase 2: R = D @ T, then row-normalize
    gemm_mfma_kernel<<<dim3(BATCH / 32, NSPL), 64, 0, stream>>>(D, TTp, flag, rtab, ctab, Rp16);
    gemm_fp32_kernel<<<dim3(BATCH / 32, 4), 256, 0, stream>>>(D, Tf, flag, Rq);
    reduce_norm16_kernel<<<BATCH, 128, 0, stream>>>(Rp16, flag, out);
    reduce_norm4f_kernel<<<BATCH, 128, 0, stream>>>(Rq, flag, out);
}